// Round 1
// baseline (96.637 us; speedup 1.0000x reference)
//
#include <hip/hip_runtime.h>

// CausalGraphLayer: out[b,n,t,c] = tanh( sum_k z[b, idx[n,k], t, c] * w[n,k,c] )
//   w[n,k,c] = adj[n,k] * sum_bb cc[c,bb] * bw[bb,n,k]
// Shapes: B=2, N=2048, T=32, C=32, NUM_BASES=4, MAX_K=32, K_CURR=16.

constexpr int BB_    = 2;     // batch
constexpr int NN_    = 2048;
constexpr int TT_    = 32;
constexpr int CC_    = 32;
constexpr int NBASE_ = 4;
constexpr int MAXK_  = 32;
constexpr int KC_    = 16;

__device__ __forceinline__ float fast_tanh(float x) {
    // tanh(x) = 1 - 2/(exp(2x)+1); saturates correctly: e->inf => 1, e->0 => -1
    float e = __expf(2.0f * x);                 // v_exp_f32 path
    float r = __builtin_amdgcn_rcpf(e + 1.0f);  // ~1 ulp approx, fine vs 1.45e-2 threshold
    return fmaf(-2.0f, r, 1.0f);
}

__global__ __launch_bounds__(256) void cgl_kernel(
    const float* __restrict__ z,     // [B,N,T,C]
    const int*   __restrict__ nbr,   // [N,KC]
    const float* __restrict__ adj,   // [N,MAXK]
    const float* __restrict__ bw,    // [NBASE,N,MAXK]
    const float* __restrict__ cc,    // [C,NBASE]
    float*       __restrict__ out)   // [B,N,T,C]
{
    __shared__ __align__(16) float w_s[KC_][CC_];   // 2 KB edge-weight tile
    __shared__ float bw_s[NBASE_][KC_];             // 256 B
    __shared__ float cc_s[CC_ * NBASE_];            // 512 B
    __shared__ float adj_s[KC_];
    __shared__ int   idx_s[KC_];

    const int tid = threadIdx.x;
    const int blk = blockIdx.x;       // 0 .. B*N-1
    const int b   = blk >> 11;        // / N
    const int n   = blk & (NN_ - 1);

    // ---- stage small per-node tables into LDS (disjoint thread ranges) ----
    if (tid < NBASE_ * KC_) {                       // 64 threads: basis weights
        int bb = tid >> 4, k = tid & 15;
        bw_s[bb][k] = bw[((size_t)bb * NN_ + n) * MAXK_ + k];
    } else if (tid >= 64 && tid < 64 + CC_ * NBASE_) {  // 128 threads: channel coeffs
        int i = tid - 64;
        cc_s[i] = cc[i];
    } else if (tid >= 192 && tid < 192 + KC_) {     // 16 threads: adjacency + indices
        int k = tid - 192;
        adj_s[k] = adj[(size_t)n * MAXK_ + k];
        idx_s[k] = nbr[n * KC_ + k];
    }
    __syncthreads();

    // ---- compute w[k][c] = adj[k] * sum_bb cc[c,bb]*bw[bb,k]  (512 cells) ----
    {
        int i = tid;
        #pragma unroll
        for (int r = 0; r < 2; ++r, i += 256) {
            int k = i >> 5, c = i & 31;
            float s = cc_s[c * NBASE_ + 0] * bw_s[0][k]
                    + cc_s[c * NBASE_ + 1] * bw_s[1][k]
                    + cc_s[c * NBASE_ + 2] * bw_s[2][k]
                    + cc_s[c * NBASE_ + 3] * bw_s[3][k];
            w_s[k][c] = s * adj_s[k];
        }
    }
    __syncthreads();

    // ---- main gather-accumulate: each thread owns one float4 of (t,c) plane ----
    // (t,c) flattened = 1024 floats = 256 float4s; c = (4*tid) & 31 .. +3 (no wrap)
    const int c0 = (tid << 2) & 31;
    const float4* __restrict__ z4 = (const float4*)z;
    const size_t zb = (size_t)b * NN_ * (TT_ * CC_ / 4);   // float4 units

    float4 acc = make_float4(0.f, 0.f, 0.f, 0.f);
    #pragma unroll
    for (int k = 0; k < KC_; ++k) {
        const int nk = idx_s[k];
        float4 zv = z4[zb + (size_t)nk * (TT_ * CC_ / 4) + tid];  // coalesced 4 KB row
        float4 wv = *(const float4*)&w_s[k][c0];                  // broadcast, no conflict
        acc.x = fmaf(zv.x, wv.x, acc.x);
        acc.y = fmaf(zv.y, wv.y, acc.y);
        acc.z = fmaf(zv.z, wv.z, acc.z);
        acc.w = fmaf(zv.w, wv.w, acc.w);
    }

    float4 o;
    o.x = fast_tanh(acc.x);
    o.y = fast_tanh(acc.y);
    o.z = fast_tanh(acc.z);
    o.w = fast_tanh(acc.w);
    ((float4*)out)[(size_t)blk * 256 + tid] = o;
}

extern "C" void kernel_launch(void* const* d_in, const int* in_sizes, int n_in,
                              void* d_out, int out_size, void* d_ws, size_t ws_size,
                              hipStream_t stream) {
    const float* z   = (const float*)d_in[0];
    const int*   nbr = (const int*)d_in[1];
    const float* adj = (const float*)d_in[2];
    const float* bw  = (const float*)d_in[3];
    const float* cc  = (const float*)d_in[4];
    float* out = (float*)d_out;

    cgl_kernel<<<dim3(BB_ * NN_), dim3(256), 0, stream>>>(z, nbr, adj, bw, cc, out);
}

// Round 2
// 89.489 us; speedup vs baseline: 1.0799x; 1.0799x over previous
//
#include <hip/hip_runtime.h>

// CausalGraphLayer: out[b,n,t,c] = tanh( sum_k z[b, idx[n,k], t, c] * w[n,k,c] )
//   w[n,k,c] = adj[n,k] * sum_bb cc[c,bb] * bw[bb,n,k]
// Shapes: B=2, N=2048, T=32, C=32, NUM_BASES=4, MAX_K=32, K_CURR=16.
//
// R2 strategy: slice T into 4 quarters; (b, tq) has 8 combos == 8 XCDs.
// blockIdx % 8 selects (b, tq) so each XCD's gather working set is
// z[b, :, tq-slice, :] = 2 MB < 4 MB per-XCD L2 -> L2-resident gather.

constexpr int BB_    = 2;
constexpr int NN_    = 2048;
constexpr int TT_    = 32;
constexpr int CC_    = 32;
constexpr int NBASE_ = 4;
constexpr int MAXK_  = 32;
constexpr int KC_    = 16;

constexpr int TQ_      = 4;                 // t-quarters
constexpr int SLICE_F4 = (TT_ / TQ_) * CC_ / 4;   // 64 float4 per node-slice
constexpr int NODES_PB = 4;                 // nodes per block (1 per wave)

__device__ __forceinline__ float fast_tanh(float x) {
    float e = __expf(2.0f * x);
    float r = __builtin_amdgcn_rcpf(e + 1.0f);
    return fmaf(-2.0f, r, 1.0f);
}

__global__ __launch_bounds__(256) void cgl_kernel(
    const float* __restrict__ z,     // [B,N,T,C]
    const int*   __restrict__ nbr,   // [N,KC]
    const float* __restrict__ adj,   // [N,MAXK]
    const float* __restrict__ bw,    // [NBASE,N,MAXK]
    const float* __restrict__ cc,    // [C,NBASE]
    float*       __restrict__ out)   // [B,N,T,C]
{
    __shared__ __align__(16) float w_s[NODES_PB][KC_][CC_];  // 8 KB
    __shared__ float bw_s[NODES_PB][NBASE_][KC_];            // 1 KB
    __shared__ float cc_s[NBASE_ * CC_];                     // 512 B, TRANSPOSED [bb][c]
    __shared__ float adj_s[NODES_PB][KC_];
    __shared__ int   idx_s[NODES_PB][KC_];

    const int tid = threadIdx.x;
    const int blk = blockIdx.x;

    // XCD-pinned (b, tq): blockIdx % 8 maps round-robin to the 8 XCDs.
    const int xcd   = blk & 7;
    const int b     = xcd >> 2;          // 0..1
    const int tq    = xcd & 3;           // 0..3
    const int group = blk >> 3;          // 0..511 -> node group of 4
    const int node0 = group * NODES_PB;

    // ---- stage per-node tables ----
    {   // bw: 256 values, one per thread: node | bb | k
        int nd = tid >> 6, bb = (tid >> 4) & 3, k = tid & 15;
        bw_s[nd][bb][k] = bw[((size_t)bb * NN_ + (node0 + nd)) * MAXK_ + k];

        if (tid < 64) {                          // adj: node|k
            int nd2 = tid >> 4, k2 = tid & 15;
            adj_s[nd2][k2] = adj[(size_t)(node0 + nd2) * MAXK_ + k2];
        } else if (tid < 128) {                  // idx: node|k
            int i = tid - 64, nd2 = i >> 4, k2 = i & 15;
            idx_s[nd2][k2] = nbr[(node0 + nd2) * KC_ + k2];
        } else {                                 // cc transposed: [bb][c]
            int i = tid - 128, bb2 = i >> 5, c2 = i & 31;
            cc_s[bb2 * CC_ + c2] = cc[c2 * NBASE_ + bb2];
        }
    }
    __syncthreads();

    // ---- compute w[nd][k][c]: 2048 cells, 8 per thread ----
    {
        int i = tid;
        #pragma unroll
        for (int r = 0; r < 8; ++r, i += 256) {
            int nd = i >> 9, k = (i >> 5) & 15, c = i & 31;
            float s = cc_s[0 * CC_ + c] * bw_s[nd][0][k]
                    + cc_s[1 * CC_ + c] * bw_s[nd][1][k]
                    + cc_s[2 * CC_ + c] * bw_s[nd][2][k]
                    + cc_s[3 * CC_ + c] * bw_s[nd][3][k];
            w_s[nd][k][c] = s * adj_s[nd][k];
        }
    }
    __syncthreads();

    // ---- main gather: wave = one node, lane = one float4 of the 8x32 slice ----
    const int wave = tid >> 6;
    const int lane = tid & 63;
    const int n    = node0 + wave;
    const int c0   = (lane << 2) & 31;          // c of this float4

    const float4* __restrict__ z4 = (const float4*)z;
    // float4 offset within a (b, row) plane: tq*64 + lane
    const size_t plane = (size_t)(TT_ * CC_ / 4);          // 256 float4 per row
    const size_t zb    = (size_t)b * NN_ * plane + (size_t)tq * SLICE_F4 + lane;

    float4 acc = make_float4(0.f, 0.f, 0.f, 0.f);
    #pragma unroll
    for (int k = 0; k < KC_; ++k) {
        const int nk = idx_s[wave][k];
        float4 zv = z4[zb + (size_t)nk * plane];           // 1 KB/wave, coalesced
        float4 wv = *(const float4*)&w_s[wave][k][c0];     // 8-way broadcast, no conflict
        acc.x = fmaf(zv.x, wv.x, acc.x);
        acc.y = fmaf(zv.y, wv.y, acc.y);
        acc.z = fmaf(zv.z, wv.z, acc.z);
        acc.w = fmaf(zv.w, wv.w, acc.w);
    }

    float4 o;
    o.x = fast_tanh(acc.x);
    o.y = fast_tanh(acc.y);
    o.z = fast_tanh(acc.z);
    o.w = fast_tanh(acc.w);

    ((float4*)out)[(size_t)b * NN_ * plane + (size_t)n * plane + tq * SLICE_F4 + lane] = o;
}

extern "C" void kernel_launch(void* const* d_in, const int* in_sizes, int n_in,
                              void* d_out, int out_size, void* d_ws, size_t ws_size,
                              hipStream_t stream) {
    const float* z   = (const float*)d_in[0];
    const int*   nbr = (const int*)d_in[1];
    const float* adj = (const float*)d_in[2];
    const float* bw  = (const float*)d_in[3];
    const float* cc  = (const float*)d_in[4];
    float* out = (float*)d_out;

    // 8 (b,tq) combos x 512 node-groups = 4096 blocks
    cgl_kernel<<<dim3(BB_ * TQ_ * (NN_ / NODES_PB)), dim3(256), 0, stream>>>(
        z, nbr, adj, bw, cc, out);
}